// Round 1
// baseline (2076.470 us; speedup 1.0000x reference)
//
#include <hip/hip_runtime.h>

#define VOCAB   32000
#define BSZ     8
#define SEQLEN  2048
#define BOS_ID  1

// ---------------------------------------------------------------- zero counts
__global__ void wm_zero_counts(int* __restrict__ counts) {
    int i = blockIdx.x * blockDim.x + threadIdx.x;
    if (i < BSZ * VOCAB) counts[i] = 0;
}

// ---------------------------------------------------------------- histogram
// One block per batch row; 2048 tokens/row, atomicAdd into global counts.
__global__ void wm_histogram(const int* __restrict__ ids, int* __restrict__ counts) {
    const int b = blockIdx.x;
    const int* row = ids + b * SEQLEN;
    int* cnt = counts + b * VOCAB;
    for (int s = threadIdx.x; s < SEQLEN; s += blockDim.x) {
        int t = row[s];
        if (t != 0 && t != BOS_ID) atomicAdd(&cnt[t], 1);
    }
}

// ---------------------------------------------------------------- argmax
// One block per row. Tie-break: higher count wins; equal count -> lower index.
// All-zero counts (no valid token) -> BOS_ID.
__global__ void wm_argmax(const int* __restrict__ counts, int* __restrict__ pred) {
    const int b = blockIdx.x;
    const int* cnt = counts + b * VOCAB;

    int best_c = 0;
    int best_i = VOCAB;  // sentinel larger than any real index
    for (int v = threadIdx.x; v < VOCAB; v += blockDim.x) {
        int c = cnt[v];
        if (c > best_c || (c == best_c && v < best_i)) { best_c = c; best_i = v; }
    }

    __shared__ int sc[256];
    __shared__ int si[256];
    sc[threadIdx.x] = best_c;
    si[threadIdx.x] = best_i;
    __syncthreads();
    for (int off = 128; off > 0; off >>= 1) {
        if ((int)threadIdx.x < off) {
            int c2 = sc[threadIdx.x + off];
            int i2 = si[threadIdx.x + off];
            if (c2 > sc[threadIdx.x] || (c2 == sc[threadIdx.x] && i2 < si[threadIdx.x])) {
                sc[threadIdx.x] = c2;
                si[threadIdx.x] = i2;
            }
        }
        __syncthreads();
    }
    if (threadIdx.x == 0) {
        pred[b] = (sc[0] == 0) ? BOS_ID : si[0];
    }
}

// ---------------------------------------------------------------- bulk fill
// Grid-stride float4 stores of -6.0f over the whole output. This is the hot
// kernel: 2.097 GB of pure coalesced writes, HBM-write-bound.
__global__ void wm_fill(float4* __restrict__ out, long long n4) {
    long long i = (long long)blockIdx.x * blockDim.x + threadIdx.x;
    const long long stride = (long long)gridDim.x * blockDim.x;
    const float4 val = make_float4(-6.0f, -6.0f, -6.0f, -6.0f);
    for (; i < n4; i += stride) out[i] = val;
}

// ---------------------------------------------------------------- spike
// 16384 scattered stores of +6 at out[b, s, pred[b]].
__global__ void wm_spike(float* __restrict__ out, const int* __restrict__ pred) {
    int i = blockIdx.x * blockDim.x + threadIdx.x;  // [0, BSZ*SEQLEN)
    if (i < BSZ * SEQLEN) {
        int b = i / SEQLEN;
        out[(long long)i * VOCAB + pred[b]] = 6.0f;
    }
}

extern "C" void kernel_launch(void* const* d_in, const int* in_sizes, int n_in,
                              void* d_out, int out_size, void* d_ws, size_t ws_size,
                              hipStream_t stream) {
    const int* ids = (const int*)d_in[0];
    float* out = (float*)d_out;

    // workspace layout: [counts: BSZ*VOCAB ints][pred: BSZ ints]
    int* counts = (int*)d_ws;
    int* pred   = counts + BSZ * VOCAB;

    // 1) zero counts (ws is poisoned to 0xAA before every call)
    {
        int n = BSZ * VOCAB;
        wm_zero_counts<<<(n + 255) / 256, 256, 0, stream>>>(counts);
    }
    // 2) per-row histogram
    wm_histogram<<<BSZ, 256, 0, stream>>>(ids, counts);
    // 3) per-row argmax with tie-break + empty fallback
    wm_argmax<<<BSZ, 256, 0, stream>>>(counts, pred);
    // 4) bulk fill of -6 (the 2.1 GB write)
    {
        const long long n4 = (long long)BSZ * SEQLEN * VOCAB / 4;  // 131,072,000
        wm_fill<<<32768, 256, 0, stream>>>((float4*)out, n4);
    }
    // 5) write the +6 spikes
    {
        int n = BSZ * SEQLEN;
        wm_spike<<<(n + 255) / 256, 256, 0, stream>>>(out, pred);
    }
}